// Round 1
// baseline (711.408 us; speedup 1.0000x reference)
//
#include <hip/hip_runtime.h>
#include <math.h>

// VQVAE graph-transformer forward, fp32 throughout.
// B=4 N=128 DIM=256 HEADS=8 DH=64 EDGE=64 DEPTH=2 K=512 INNER=512
// Key algebraic rewrite: ekv = e@w_ekv is NEVER materialized.
//   sim contribution:  q . (e_ij @ w_h) = (q @ w_h^T) . e_ij   (precomputed qe)
//   out contribution:  sum_j att_j (e_ij @ w_h + b_h) = (sum_j att_j e_ij) @ w_h + b_h

#define DEV __device__ __forceinline__

constexpr int Bn = 4, Nn = 128, DIMn = 256, HEADSn = 8, DHn = 64, EDGEn = 64,
              DEPTHn = 2, Kn = 512, INNERn = 512;

DEV float wave_reduce_sum(float v) {
#pragma unroll
  for (int m = 32; m >= 1; m >>= 1) v += __shfl_xor(v, m);
  return v;
}

// 256-thread block sum, broadcast to all threads. red must be float[4].
DEV float block_reduce_sum_256(float v, float* red) {
  v = wave_reduce_sum(v);
  int tid = threadIdx.x;
  if ((tid & 63) == 0) red[tid >> 6] = v;
  __syncthreads();
  v = red[0] + red[1] + red[2] + red[3];
  __syncthreads();  // allow red reuse by caller
  return v;
}

// ---------------------------------------------------------------------------
// Edge LayerNorm: edges (B,EDGE,N,N) -> e stored as [b][i][c][j] so that
// (a) reads/writes here are j-coalesced, (b) attention sim reads (fixed c,
// lanes j) are coalesced/conflict-free.
__global__ __launch_bounds__(256) void edge_ln_kernel(
    const float* __restrict__ edges, const float* __restrict__ g,
    const float* __restrict__ bta, float* __restrict__ e) {
  int t = blockIdx.x * 256 + threadIdx.x;  // (b,i,j) flat, 65536 total
  int j = t & 127;
  int i = (t >> 7) & 127;
  int b = t >> 14;
  const float* src = edges + (size_t)b * EDGEn * Nn * Nn + i * Nn + j;
  float vals[EDGEn];
  float s = 0.f;
#pragma unroll
  for (int c = 0; c < EDGEn; ++c) {
    float x = src[(size_t)c * (Nn * Nn)];
    vals[c] = x;
    s += x;
  }
  float m = s * (1.0f / 64.0f);
  float s2 = 0.f;
#pragma unroll
  for (int c = 0; c < EDGEn; ++c) {
    float d = vals[c] - m;
    s2 += d * d;
  }
  float inv = 1.f / sqrtf(s2 * (1.0f / 64.0f) + 1e-5f);
  float* dst = e + ((size_t)(b * Nn + i) * EDGEn) * Nn + j;
#pragma unroll
  for (int c = 0; c < EDGEn; ++c)
    dst[(size_t)c * Nn] = (vals[c] - m) * inv * g[c] + bta[c];
}

// ---------------------------------------------------------------------------
// Rotary tables: cos/sin[n][p], p=0..31 (pairs), fr = n * 10000^(-2p/64)
__global__ void rope_table_kernel(float* __restrict__ cost,
                                  float* __restrict__ sint) {
  int t = blockIdx.x * 256 + threadIdx.x;
  if (t >= Nn * 32) return;
  int n = t >> 5, p = t & 31;
  float inv = powf(10000.f, -(float)(2 * p) / 64.f);
  float fr = (float)n * inv;
  cost[t] = cosf(fr);
  sint[t] = sinf(fr);
}

// ---------------------------------------------------------------------------
// Row LayerNorm over DIM=256, one 256-thread block per row.
__global__ __launch_bounds__(256) void ln_kernel(const float* __restrict__ x,
                                                 const float* __restrict__ g,
                                                 const float* __restrict__ b,
                                                 float* __restrict__ y) {
  __shared__ float red[4];
  int row = blockIdx.x, tid = threadIdx.x;
  float v = x[(size_t)row * DIMn + tid];
  float m = block_reduce_sum_256(v, red) * (1.0f / 256.0f);
  float d = v - m;
  float var = block_reduce_sum_256(d * d, red) * (1.0f / 256.0f);
  float inv = 1.f / sqrtf(var + 1e-5f);
  y[(size_t)row * DIMn + tid] = d * inv * g[tid] + b[tid];
}

// ---------------------------------------------------------------------------
// fp32 GEMM C[M,N] = A[M,K] @ W[K,N] + bias, optional exact GELU.
// 64x64 tile / 256 threads / BK=16, 4x4 microtile. M,N,K multiples of 64/16.
__global__ __launch_bounds__(256) void gemm_kernel(
    const float* __restrict__ A, const float* __restrict__ W,
    const float* __restrict__ bias, float* __restrict__ C, int M, int N, int K,
    int act) {
  __shared__ __align__(16) float As[16][68];  // [kk][m], padded
  __shared__ __align__(16) float Bs[16][68];  // [kk][n], padded
  int tid = threadIdx.x;
  int bx = blockIdx.x, by = blockIdx.y;
  int tx = tid & 15, ty = tid >> 4;
  int arow = tid >> 2, acol = (tid & 3) << 2;
  int brow = tid >> 4, bcol = (tid & 15) << 2;
  float acc[4][4] = {};
  for (int k0 = 0; k0 < K; k0 += 16) {
    float4 a4 = *(const float4*)(A + (size_t)(by * 64 + arow) * K + k0 + acol);
    As[acol + 0][arow] = a4.x;
    As[acol + 1][arow] = a4.y;
    As[acol + 2][arow] = a4.z;
    As[acol + 3][arow] = a4.w;
    float4 b4 = *(const float4*)(W + (size_t)(k0 + brow) * N + bx * 64 + bcol);
    *(float4*)&Bs[brow][bcol] = b4;
    __syncthreads();
#pragma unroll
    for (int kk = 0; kk < 16; ++kk) {
      float4 av = *(const float4*)&As[kk][ty * 4];
      float4 bv = *(const float4*)&Bs[kk][tx * 4];
      float a[4] = {av.x, av.y, av.z, av.w};
      float bb[4] = {bv.x, bv.y, bv.z, bv.w};
#pragma unroll
      for (int u = 0; u < 4; ++u)
#pragma unroll
        for (int w = 0; w < 4; ++w) acc[u][w] += a[u] * bb[w];
    }
    __syncthreads();
  }
#pragma unroll
  for (int u = 0; u < 4; ++u) {
    int r = by * 64 + ty * 4 + u;
    int cc = bx * 64 + tx * 4;
    float4 o;
    float* op = (float*)&o;
#pragma unroll
    for (int w = 0; w < 4; ++w) {
      float x = acc[u][w] + bias[cc + w];
      if (act == 1) x = 0.5f * x * (1.f + erff(x * 0.70710678118654752f));
      op[w] = x;
    }
    *(float4*)(C + (size_t)r * N + cc) = o;
  }
}

// ---------------------------------------------------------------------------
// In-place rotary on q (rows x 512) and k (= first 512 cols of kv, stride 1024)
__global__ __launch_bounds__(256) void rope_apply_kernel(
    float* __restrict__ q, float* __restrict__ kv,
    const float* __restrict__ cost, const float* __restrict__ sint) {
  int row = blockIdx.x;    // b*128+n, 512 rows
  int tid = threadIdx.x;   // 8 heads * 32 pairs
  int h = tid >> 5, p = tid & 31;
  int n = row & 127;
  float c = cost[n * 32 + p], s = sint[n * 32 + p];
  int col = h * 64 + 2 * p;
  float* qp = q + (size_t)row * INNERn + col;
  float x1 = qp[0], x2 = qp[1];
  qp[0] = x1 * c - x2 * s;
  qp[1] = x2 * c + x1 * s;
  float* kp = kv + (size_t)row * (2 * INNERn) + col;
  x1 = kp[0];
  x2 = kp[1];
  kp[0] = x1 * c - x2 * s;
  kp[1] = x2 * c + x1 * s;
}

// ---------------------------------------------------------------------------
// qe[b,h,i,c] = sum_d q_rot[b,i,h*64+d] * w_ekv[c, h*64+d]. One block per (b,h).
__global__ __launch_bounds__(256) void qe_kernel(const float* __restrict__ q,
                                                 const float* __restrict__ wek,
                                                 float* __restrict__ qe) {
  __shared__ float qs[128 * 65];
  __shared__ float ws[64 * 65];
  int bh = blockIdx.x;  // b*8+h
  int b = bh >> 3, h = bh & 7;
  int tid = threadIdx.x;
  for (int f = tid; f < 128 * 64; f += 256) {
    int i = f >> 6, d = f & 63;
    qs[i * 65 + d] = q[(size_t)(b * 128 + i) * INNERn + h * 64 + d];
  }
  for (int f = tid; f < 64 * 64; f += 256) {
    int c = f >> 6, d = f & 63;
    ws[c * 65 + d] = wek[(size_t)c * INNERn + h * 64 + d];
  }
  __syncthreads();
  int c = tid & 63, iq = tid >> 6;
  for (int ib = 0; ib < 32; ++ib) {
    int i = ib * 4 + iq;
    float acc = 0.f;
#pragma unroll
    for (int d = 0; d < 64; ++d) acc += qs[i * 65 + d] * ws[c * 65 + d];
    qe[((size_t)bh * 128 + i) * 64 + c] = acc;
  }
}

// ---------------------------------------------------------------------------
// Fused attention: one 128-thread block per (b,h,i) row.
//   sim_j = 0.125*(q_i.k_j + qe_i.e_ij)   (q.b_ekv const dropped: softmax-inv)
//   att = softmax(sim); out = sum att_j v_j + (sum att_j e_ij)@w_h + b_h
__global__ __launch_bounds__(128) void attn_kernel(
    const float* __restrict__ q, const float* __restrict__ kv,
    const float* __restrict__ qe, const float* __restrict__ e,
    const float* __restrict__ wek, const float* __restrict__ bek,
    float* __restrict__ attn_out) {
  __shared__ __align__(16) float qs[64];
  __shared__ float qes[64];
  __shared__ float es[64 * 129];  // [c][j], padded: phase A & C conflict-free
  __shared__ float att[128];
  __shared__ float red[4];
  __shared__ float avh[2][64], aeh[2][64], aef[64];
  int blk = blockIdx.x;
  int i = blk & 127, h = (blk >> 7) & 7, b = blk >> 10;
  int tid = threadIdx.x;
  if (tid < 64) {
    qs[tid] = q[(size_t)(b * 128 + i) * INNERn + h * 64 + tid];
    qes[tid] = qe[((size_t)(b * 8 + h) * 128 + i) * 64 + tid];
  }
  for (int f = tid; f < 64 * 128; f += 128) {
    int c = f >> 7, j = f & 127;
    es[c * 129 + j] = e[((size_t)(b * 128 + i) * 64 + c) * 128 + j];
  }
  __syncthreads();
  // --- phase A: sim for j = tid (k read direct from global, L1/L2-hot slice)
  int j = tid;
  float s = 0.f;
  const float4* krow = (const float4*)(kv + (size_t)(b * 128 + j) * 1024 + h * 64);
  const float4* qs4 = (const float4*)qs;
#pragma unroll
  for (int t4 = 0; t4 < 16; ++t4) {
    float4 k4 = krow[t4];
    float4 q4 = qs4[t4];
    s += q4.x * k4.x + q4.y * k4.y + q4.z * k4.z + q4.w * k4.w;
  }
#pragma unroll
  for (int c = 0; c < 64; ++c) s += qes[c] * es[c * 129 + j];
  s *= 0.125f;
  // --- phase B: softmax over 128 (2 waves)
  float mx = s;
#pragma unroll
  for (int m = 32; m >= 1; m >>= 1) mx = fmaxf(mx, __shfl_xor(mx, m));
  if ((tid & 63) == 0) red[tid >> 6] = mx;
  __syncthreads();
  mx = fmaxf(red[0], red[1]);
  float p = expf(s - mx);
  float sm = wave_reduce_sum(p);
  if ((tid & 63) == 0) red[2 + (tid >> 6)] = sm;
  __syncthreads();
  float denom = red[2] + red[3];
  att[tid] = p / denom;
  __syncthreads();
  // --- phase C: av[d] = sum att_j v[j][d]; ae[c] = sum att_j e[c][j]
  int d = tid & 63, half = tid >> 6;
  const float* vbase = kv + (size_t)b * 128 * 1024 + 512 + h * 64 + d;
  float av = 0.f, ae = 0.f;
#pragma unroll 8
  for (int jj = 0; jj < 64; ++jj) {
    int jx = half * 64 + jj;
    float a = att[jx];
    av += a * vbase[(size_t)jx * 1024];
    ae += a * es[d * 129 + jx];  // d plays role of channel c
  }
  avh[half][d] = av;
  aeh[half][d] = ae;
  __syncthreads();
  if (tid < 64) aef[tid] = aeh[0][tid] + aeh[1][tid];
  __syncthreads();
  if (tid < 64) {
    float o = avh[0][tid] + avh[1][tid] + bek[h * 64 + tid];
    const float* wcol = wek + h * 64 + tid;
#pragma unroll
    for (int c = 0; c < 64; ++c) o += aef[c] * wcol[(size_t)c * INNERn];
    attn_out[(size_t)(b * 128 + i) * INNERn + h * 64 + tid] = o;
  }
}

// ---------------------------------------------------------------------------
// Gated residual: g = sigmoid([x, res, x-res] @ gw); nodes = x*g + res*(1-g)
__global__ __launch_bounds__(256) void gate_kernel(const float* __restrict__ x,
                                                   float* __restrict__ nodes,
                                                   const float* __restrict__ gw) {
  __shared__ float red[4];
  int row = blockIdx.x, tid = threadIdx.x;
  float xv = x[(size_t)row * DIMn + tid];
  float rv = nodes[(size_t)row * DIMn + tid];
  float pv = xv * gw[tid] + rv * gw[DIMn + tid] + (xv - rv) * gw[2 * DIMn + tid];
  float ssum = block_reduce_sum_256(pv, red);
  float gsig = 1.f / (1.f + expf(-ssum));
  nodes[(size_t)row * DIMn + tid] = xv * gsig + rv * (1.f - gsig);
}

// ---------------------------------------------------------------------------
// VQ nearest neighbor: d_k = |z|^2 + sum(c*(c-2z)); first-min argmin; copy row.
__global__ __launch_bounds__(256) void vq_kernel(
    const float* __restrict__ nodes, const float* __restrict__ codebook,
    float* __restrict__ out) {
  __shared__ float zs[256];
  __shared__ float red[4];
  __shared__ float wmin[4];
  __shared__ int widx[4];
  int row = blockIdx.x, tid = threadIdx.x;
  float zv = nodes[(size_t)row * DIMn + tid];
  zs[tid] = zv;
  float zz = block_reduce_sum_256(zv * zv, red);  // syncs; zs now visible
  int lane = tid & 63, w = tid >> 6;
  float best = INFINITY;
  int bidx = 0;
  for (int k = w; k < Kn; k += 4) {
    const float* c = codebook + (size_t)k * DIMn;
    float pacc = 0.f;
#pragma unroll
    for (int u = 0; u < 4; ++u) {
      float cv = c[u * 64 + lane];
      pacc += cv * (cv - 2.f * zs[u * 64 + lane]);
    }
    pacc = wave_reduce_sum(pacc);
    float dk = zz + pacc;
    if (dk < best) {  // strict <: keeps first (lowest k) min within wave
      best = dk;
      bidx = k;
    }
  }
  if (lane == 0) {
    wmin[w] = best;
    widx[w] = bidx;
  }
  __syncthreads();
  if (tid == 0) {
    float bb = wmin[0];
    int bi = widx[0];
    for (int t = 1; t < 4; ++t)
      if (wmin[t] < bb || (wmin[t] == bb && widx[t] < bi)) {
        bb = wmin[t];
        bi = widx[t];
      }
    widx[0] = bi;
  }
  __syncthreads();
  int idx = widx[0];
  float zq = codebook[(size_t)idx * DIMn + tid];
  out[(size_t)row * DIMn + tid] = zv + (zq - zv);  // faithful to reference
}

// ---------------------------------------------------------------------------
extern "C" void kernel_launch(void* const* d_in, const int* in_sizes, int n_in,
                              void* d_out, int out_size, void* d_ws,
                              size_t ws_size, hipStream_t stream) {
  const float* nodes_in = (const float*)d_in[0];
  const float* edges = (const float*)d_in[1];
  const float* edge_ln_g = (const float*)d_in[2];
  const float* edge_ln_b = (const float*)d_in[3];
  const float* ln1_g = (const float*)d_in[4];
  const float* ln1_b = (const float*)d_in[5];
  const float* w_exp = (const float*)d_in[6];
  const float* b_exp = (const float*)d_in[7];
  const float* w_q = (const float*)d_in[8];
  const float* b_q = (const float*)d_in[9];
  const float* w_kv = (const float*)d_in[10];
  const float* b_kv = (const float*)d_in[11];
  const float* w_ekv = (const float*)d_in[12];
  const float* b_ekv = (const float*)d_in[13];
  const float* w_out = (const float*)d_in[14];
  const float* b_out = (const float*)d_in[15];
  const float* gate1_w = (const float*)d_in[16];
  const float* ln2_g = (const float*)d_in[17];
  const float* ln2_b = (const float*)d_in[18];
  const float* w_ff1 = (const float*)d_in[19];
  const float* b_ff1 = (const float*)d_in[20];
  const float* w_ff2 = (const float*)d_in[21];
  const float* b_ff2 = (const float*)d_in[22];
  const float* gate2_w = (const float*)d_in[23];
  const float* codebook = (const float*)d_in[24];

  // workspace layout (floats); total ~6.7M floats = ~27 MB
  float* ws = (float*)d_ws;
  float* e_buf = ws;                    // 4*128*64*128 = 4194304
  float* cost = e_buf + 4194304;        // 4096
  float* sint = cost + 4096;            // 4096
  float* nodes = sint + 4096;           // 131072 (mutable residual stream)
  float* xln = nodes + 131072;          // 131072 (ln1 / ln2 output)
  float* xe = xln + 131072;             // 262144
  float* qb = xe + 262144;              // 262144
  float* kvb = qb + 262144;             // 524288 (k cols 0..511, v 512..1023)
  float* qeb = kvb + 524288;            // 262144
  float* attn = qeb + 262144;           // 262144
  float* proj = attn + 262144;          // 131072 (out-proj / ff2 result)
  float* ff1 = proj + 131072;           // 524288

  hipMemcpyAsync(nodes, nodes_in, sizeof(float) * Bn * Nn * DIMn,
                 hipMemcpyDeviceToDevice, stream);
  edge_ln_kernel<<<256, 256, 0, stream>>>(edges, edge_ln_g, edge_ln_b, e_buf);
  rope_table_kernel<<<16, 256, 0, stream>>>(cost, sint);

  for (int l = 0; l < DEPTHn; ++l) {
    ln_kernel<<<512, 256, 0, stream>>>(nodes, ln1_g + l * 256, ln1_b + l * 256,
                                       xln);
    gemm_kernel<<<dim3(8, 8), 256, 0, stream>>>(
        xln, w_exp + l * 256 * 512, b_exp + l * 512, xe, 512, 512, 256, 0);
    gemm_kernel<<<dim3(8, 8), 256, 0, stream>>>(
        xe, w_q + l * 512 * 512, b_q + l * 512, qb, 512, 512, 512, 0);
    gemm_kernel<<<dim3(16, 8), 256, 0, stream>>>(
        xe, w_kv + l * 512 * 1024, b_kv + l * 1024, kvb, 512, 1024, 512, 0);
    rope_apply_kernel<<<512, 256, 0, stream>>>(qb, kvb, cost, sint);
    qe_kernel<<<32, 256, 0, stream>>>(qb, w_ekv + l * 64 * 512, qeb);
    attn_kernel<<<4096, 128, 0, stream>>>(qb, kvb, qeb, e_buf,
                                          w_ekv + l * 64 * 512,
                                          b_ekv + l * 512, attn);
    gemm_kernel<<<dim3(4, 8), 256, 0, stream>>>(
        attn, w_out + l * 512 * 256, b_out + l * 256, proj, 512, 256, 512, 0);
    gate_kernel<<<512, 256, 0, stream>>>(proj, nodes, gate1_w + l * 768);
    ln_kernel<<<512, 256, 0, stream>>>(nodes, ln2_g + l * 256, ln2_b + l * 256,
                                       xln);
    gemm_kernel<<<dim3(16, 8), 256, 0, stream>>>(
        xln, w_ff1 + l * 256 * 1024, b_ff1 + l * 1024, ff1, 512, 1024, 256, 1);
    gemm_kernel<<<dim3(4, 8), 256, 0, stream>>>(
        ff1, w_ff2 + l * 1024 * 256, b_ff2 + l * 256, proj, 512, 256, 1024, 0);
    gate_kernel<<<512, 256, 0, stream>>>(proj, nodes, gate2_w + l * 768);
  }
  vq_kernel<<<512, 256, 0, stream>>>(nodes, codebook, (float*)d_out);
}

// Round 2
// 487.827 us; speedup vs baseline: 1.4583x; 1.4583x over previous
//
#include <hip/hip_runtime.h>
#include <math.h>

// VQVAE graph-transformer forward, fp32 throughout.
// B=4 N=128 DIM=256 HEADS=8 DH=64 EDGE=64 DEPTH=2 K=512 INNER=512
// ekv = e@w_ekv never materialized (qe pre-contraction + ae post-contraction).
// R2: vq rewritten (no inner wave-reduce), gemm 32x64 tiles (2x blocks),
//     rope fused into gemm epilogue, LN fused into gate kernel.

#define DEV __device__ __forceinline__

constexpr int Bn = 4, Nn = 128, DIMn = 256, HEADSn = 8, DHn = 64, EDGEn = 64,
              DEPTHn = 2, Kn = 512, INNERn = 512;

DEV float wave_reduce_sum(float v) {
#pragma unroll
  for (int m = 32; m >= 1; m >>= 1) v += __shfl_xor(v, m);
  return v;
}

// 256-thread block sum, broadcast to all threads. red must be float[4].
DEV float block_reduce_sum_256(float v, float* red) {
  v = wave_reduce_sum(v);
  int tid = threadIdx.x;
  if ((tid & 63) == 0) red[tid >> 6] = v;
  __syncthreads();
  v = red[0] + red[1] + red[2] + red[3];
  __syncthreads();  // allow red reuse by caller
  return v;
}

// ---------------------------------------------------------------------------
// Edge LayerNorm: edges (B,EDGE,N,N) -> e stored as [b][i][c][j].
__global__ __launch_bounds__(256) void edge_ln_kernel(
    const float* __restrict__ edges, const float* __restrict__ g,
    const float* __restrict__ bta, float* __restrict__ e) {
  int t = blockIdx.x * 256 + threadIdx.x;  // (b,i,j) flat, 65536 total
  int j = t & 127;
  int i = (t >> 7) & 127;
  int b = t >> 14;
  const float* src = edges + (size_t)b * EDGEn * Nn * Nn + i * Nn + j;
  float vals[EDGEn];
  float s = 0.f;
#pragma unroll
  for (int c = 0; c < EDGEn; ++c) {
    float x = src[(size_t)c * (Nn * Nn)];
    vals[c] = x;
    s += x;
  }
  float m = s * (1.0f / 64.0f);
  float s2 = 0.f;
#pragma unroll
  for (int c = 0; c < EDGEn; ++c) {
    float d = vals[c] - m;
    s2 += d * d;
  }
  float inv = 1.f / sqrtf(s2 * (1.0f / 64.0f) + 1e-5f);
  float* dst = e + ((size_t)(b * Nn + i) * EDGEn) * Nn + j;
#pragma unroll
  for (int c = 0; c < EDGEn; ++c)
    dst[(size_t)c * Nn] = (vals[c] - m) * inv * g[c] + bta[c];
}

// ---------------------------------------------------------------------------
// Rotary tables: cos/sin[n][p], p=0..31 (pairs), fr = n * 10000^(-2p/64)
__global__ void rope_table_kernel(float* __restrict__ cost,
                                  float* __restrict__ sint) {
  int t = blockIdx.x * 256 + threadIdx.x;
  if (t >= Nn * 32) return;
  int n = t >> 5, p = t & 31;
  float inv = powf(10000.f, -(float)(2 * p) / 64.f);
  float fr = (float)n * inv;
  cost[t] = cosf(fr);
  sint[t] = sinf(fr);
}

// ---------------------------------------------------------------------------
// Row LayerNorm over DIM=256, one 256-thread block per row (layer-0 entry only)
__global__ __launch_bounds__(256) void ln_kernel(const float* __restrict__ x,
                                                 const float* __restrict__ g,
                                                 const float* __restrict__ b,
                                                 float* __restrict__ y) {
  __shared__ float red[4];
  int row = blockIdx.x, tid = threadIdx.x;
  float v = x[(size_t)row * DIMn + tid];
  float m = block_reduce_sum_256(v, red) * (1.0f / 256.0f);
  float d = v - m;
  float var = block_reduce_sum_256(d * d, red) * (1.0f / 256.0f);
  float inv = 1.f / sqrtf(var + 1e-5f);
  y[(size_t)row * DIMn + tid] = d * inv * g[tid] + b[tid];
}

// ---------------------------------------------------------------------------
// fp32 GEMM C[M,N] = A[M,K] @ W[K,N] + bias. 32x64 tile, BK=32, 2x4 microtile.
// act: 0 none, 1 exact gelu, 2 rope(all cols), 3 rope(cols<512 only, i.e. k of kv)
__global__ __launch_bounds__(256) void gemm_kernel(
    const float* __restrict__ A, const float* __restrict__ W,
    const float* __restrict__ bias, float* __restrict__ C, int M, int N, int K,
    int act, const float* __restrict__ cost, const float* __restrict__ sint) {
  __shared__ float As[32][34];                 // [kk][m], pad->8B align, ~2-way
  __shared__ __align__(16) float Bs[32][68];   // [kk][n]
  int tid = threadIdx.x;
  int bx = blockIdx.x, by = blockIdx.y;
  int tx = tid & 15, ty = tid >> 4;            // tx: 4 cols, ty: 2 rows
  int arow = tid >> 3, acol = (tid & 7) << 2;  // A tile 32x32
  int brow = tid >> 4, bcol = (tid & 15) << 2; // B tile 32x64 (two halves)
  float acc[2][4] = {};
  for (int k0 = 0; k0 < K; k0 += 32) {
    float4 a4 = *(const float4*)(A + (size_t)(by * 32 + arow) * K + k0 + acol);
    As[acol + 0][arow] = a4.x;
    As[acol + 1][arow] = a4.y;
    As[acol + 2][arow] = a4.z;
    As[acol + 3][arow] = a4.w;
    float4 b4 = *(const float4*)(W + (size_t)(k0 + brow) * N + bx * 64 + bcol);
    *(float4*)&Bs[brow][bcol] = b4;
    float4 b4b =
        *(const float4*)(W + (size_t)(k0 + brow + 16) * N + bx * 64 + bcol);
    *(float4*)&Bs[brow + 16][bcol] = b4b;
    __syncthreads();
#pragma unroll
    for (int kk = 0; kk < 32; ++kk) {
      float2 av = *(const float2*)&As[kk][ty * 2];
      float4 bv = *(const float4*)&Bs[kk][tx * 4];
      acc[0][0] += av.x * bv.x;
      acc[0][1] += av.x * bv.y;
      acc[0][2] += av.x * bv.z;
      acc[0][3] += av.x * bv.w;
      acc[1][0] += av.y * bv.x;
      acc[1][1] += av.y * bv.y;
      acc[1][2] += av.y * bv.z;
      acc[1][3] += av.y * bv.w;
    }
    __syncthreads();
  }
  int cc = bx * 64 + tx * 4;
#pragma unroll
  for (int u = 0; u < 2; ++u) {
    int r = by * 32 + ty * 2 + u;
    float o[4];
#pragma unroll
    for (int w = 0; w < 4; ++w) o[w] = acc[u][w] + bias[cc + w];
    if (act == 1) {
#pragma unroll
      for (int w = 0; w < 4; ++w)
        o[w] = 0.5f * o[w] * (1.f + erff(o[w] * 0.70710678118654752f));
    } else if (act == 2 || (act == 3 && cc < 512)) {
      int n = r & 127;
      int p0 = (cc & 63) >> 1;  // pair idx of (o0,o1); (o2,o3) is p0+1
      float c0 = cost[n * 32 + p0], s0 = sint[n * 32 + p0];
      float c1 = cost[n * 32 + p0 + 1], s1 = sint[n * 32 + p0 + 1];
      float x0 = o[0], x1 = o[1], x2 = o[2], x3 = o[3];
      o[0] = x0 * c0 - x1 * s0;
      o[1] = x1 * c0 + x0 * s0;
      o[2] = x2 * c1 - x3 * s1;
      o[3] = x3 * c1 + x2 * s1;
    }
    float4 o4 = {o[0], o[1], o[2], o[3]};
    *(float4*)(C + (size_t)r * N + cc) = o4;
  }
}

// ---------------------------------------------------------------------------
// qe[b,h,i,c] = sum_d q_rot[b,i,h*64+d] * w_ekv[c, h*64+d]. Block=(b,h,iq:32 rows)
__global__ __launch_bounds__(256) void qe_kernel(const float* __restrict__ q,
                                                 const float* __restrict__ wek,
                                                 float* __restrict__ qe) {
  __shared__ float qs[32 * 65];
  __shared__ float ws[64 * 65];
  int blk = blockIdx.x;  // ((b*8+h)*4 + iq)
  int iq = blk & 3;
  int bh = blk >> 2;
  int b = bh >> 3, h = bh & 7;
  int i0 = iq * 32;
  int tid = threadIdx.x;
  for (int f = tid; f < 32 * 64; f += 256) {
    int i = f >> 6, d = f & 63;
    qs[i * 65 + d] = q[(size_t)(b * 128 + i0 + i) * INNERn + h * 64 + d];
  }
  for (int f = tid; f < 64 * 64; f += 256) {
    int c = f >> 6, d = f & 63;
    ws[c * 65 + d] = wek[(size_t)c * INNERn + h * 64 + d];
  }
  __syncthreads();
  int c = tid & 63, i2 = tid >> 6;
  for (int ib = 0; ib < 8; ++ib) {
    int i = ib * 4 + i2;
    float acc = 0.f;
#pragma unroll
    for (int d = 0; d < 64; ++d) acc += qs[i * 65 + d] * ws[c * 65 + d];
    qe[((size_t)bh * 128 + i0 + i) * 64 + c] = acc;
  }
}

// ---------------------------------------------------------------------------
// Fused attention: one 128-thread block per (b,h,i) row.
__global__ __launch_bounds__(128) void attn_kernel(
    const float* __restrict__ q, const float* __restrict__ kv,
    const float* __restrict__ qe, const float* __restrict__ e,
    const float* __restrict__ wek, const float* __restrict__ bek,
    float* __restrict__ attn_out) {
  __shared__ __align__(16) float qs[64];
  __shared__ float qes[64];
  __shared__ float es[64 * 129];  // [c][j]
  __shared__ float att[128];
  __shared__ float red[4];
  __shared__ float avh[2][64], aeh[2][64], aef[64];
  int blk = blockIdx.x;
  int i = blk & 127, h = (blk >> 7) & 7, b = blk >> 10;
  int tid = threadIdx.x;
  if (tid < 64) {
    qs[tid] = q[(size_t)(b * 128 + i) * INNERn + h * 64 + tid];
    qes[tid] = qe[((size_t)(b * 8 + h) * 128 + i) * 64 + tid];
  }
  const float* ebase = e + ((size_t)(b * 128 + i) * 64) * 128;
  for (int f = tid; f < 2048; f += 128) {  // 2048 float4 = 64c x 32 groups
    int c = f >> 5, j4 = (f & 31) << 2;
    float4 v4 = *(const float4*)(ebase + (size_t)c * 128 + j4);
    es[c * 129 + j4 + 0] = v4.x;
    es[c * 129 + j4 + 1] = v4.y;
    es[c * 129 + j4 + 2] = v4.z;
    es[c * 129 + j4 + 3] = v4.w;
  }
  __syncthreads();
  // --- phase A: sim for j = tid
  int j = tid;
  float s = 0.f;
  const float4* krow =
      (const float4*)(kv + (size_t)(b * 128 + j) * 1024 + h * 64);
  const float4* qs4 = (const float4*)qs;
#pragma unroll
  for (int t4 = 0; t4 < 16; ++t4) {
    float4 k4 = krow[t4];
    float4 q4 = qs4[t4];
    s += q4.x * k4.x + q4.y * k4.y + q4.z * k4.z + q4.w * k4.w;
  }
#pragma unroll
  for (int c = 0; c < 64; ++c) s += qes[c] * es[c * 129 + j];
  s *= 0.125f;
  // --- phase B: softmax over 128 (2 waves)
  float mx = s;
#pragma unroll
  for (int m = 32; m >= 1; m >>= 1) mx = fmaxf(mx, __shfl_xor(mx, m));
  if ((tid & 63) == 0) red[tid >> 6] = mx;
  __syncthreads();
  mx = fmaxf(red[0], red[1]);
  float p = expf(s - mx);
  float sm = wave_reduce_sum(p);
  if ((tid & 63) == 0) red[2 + (tid >> 6)] = sm;
  __syncthreads();
  float denom = red[2] + red[3];
  att[tid] = p / denom;
  __syncthreads();
  // --- phase C: av[d] = sum att_j v[j][d]; ae[c] = sum att_j e[c][j]
  int d = tid & 63, half = tid >> 6;
  const float* vbase = kv + (size_t)b * 128 * 1024 + 512 + h * 64 + d;
  float av = 0.f, ae = 0.f;
#pragma unroll 8
  for (int jj = 0; jj < 64; ++jj) {
    int jx = half * 64 + jj;
    float a = att[jx];
    av += a * vbase[(size_t)jx * 1024];
    ae += a * es[d * 129 + jx];
  }
  avh[half][d] = av;
  aeh[half][d] = ae;
  __syncthreads();
  if (tid < 64) aef[tid] = aeh[0][tid] + aeh[1][tid];
  __syncthreads();
  if (tid < 64) {
    float o = avh[0][tid] + avh[1][tid] + bek[h * 64 + tid];
    const float* wcol = wek + h * 64 + tid;
#pragma unroll
    for (int c = 0; c < 64; ++c) o += aef[c] * wcol[(size_t)c * INNERn];
    attn_out[(size_t)(b * 128 + i) * INNERn + h * 64 + tid] = o;
  }
}

// ---------------------------------------------------------------------------
// Gated residual + (optional) fused LayerNorm of the result.
// nodes = x*g + res*(1-g); if lng: xln = LN(nodes)*lng + lnb
__global__ __launch_bounds__(256) void gate_ln_kernel(
    const float* __restrict__ x, float* __restrict__ nodes,
    const float* __restrict__ gw, const float* __restrict__ lng,
    const float* __restrict__ lnb, float* __restrict__ xln) {
  __shared__ float red[4];
  int row = blockIdx.x, tid = threadIdx.x;
  float xv = x[(size_t)row * DIMn + tid];
  float rv = nodes[(size_t)row * DIMn + tid];
  float pv =
      xv * gw[tid] + rv * gw[DIMn + tid] + (xv - rv) * gw[2 * DIMn + tid];
  float ssum = block_reduce_sum_256(pv, red);
  float gsig = 1.f / (1.f + expf(-ssum));
  float nv = xv * gsig + rv * (1.f - gsig);
  nodes[(size_t)row * DIMn + tid] = nv;
  if (lng) {
    float m = block_reduce_sum_256(nv, red) * (1.0f / 256.0f);
    float d = nv - m;
    float var = block_reduce_sum_256(d * d, red) * (1.0f / 256.0f);
    float inv = 1.f / sqrtf(var + 1e-5f);
    xln[(size_t)row * DIMn + tid] = d * inv * lng[tid] + lnb[tid];
  }
}

// ---------------------------------------------------------------------------
// VQ nearest neighbor, R2: thread-per-codebook-entry, no inner wave reduce.
// 4 rows per block (128 blocks). dist' = |c|^2 - 2 z.c  (|z|^2 dropped: const).
__global__ __launch_bounds__(256) void vq_kernel(
    const float* __restrict__ nodes, const float* __restrict__ codebook,
    float* __restrict__ out) {
  __shared__ __align__(16) float zs[4 * 256];
  __shared__ float wval[4][4];
  __shared__ int widx[4][4];
  __shared__ int fidx[4];
  int row0 = blockIdx.x * 4;
  int tid = threadIdx.x;
  for (int f = tid; f < 1024; f += 256)
    zs[f] = nodes[(size_t)row0 * DIMn + f];
  __syncthreads();
  int k1 = tid, k2 = tid + 256;
  const float4* c1p = (const float4*)(codebook + (size_t)k1 * DIMn);
  const float4* c2p = (const float4*)(codebook + (size_t)k2 * DIMn);
  float dot[4][2] = {};
  float cc0 = 0.f, cc1 = 0.f;
#pragma unroll 8
  for (int d4 = 0; d4 < 64; ++d4) {
    float4 c1 = c1p[d4], c2 = c2p[d4];
    cc0 += c1.x * c1.x + c1.y * c1.y + c1.z * c1.z + c1.w * c1.w;
    cc1 += c2.x * c2.x + c2.y * c2.y + c2.z * c2.z + c2.w * c2.w;
#pragma unroll
    for (int r = 0; r < 4; ++r) {
      float4 z = *(const float4*)&zs[r * 256 + d4 * 4];  // broadcast read
      dot[r][0] += c1.x * z.x + c1.y * z.y + c1.z * z.z + c1.w * z.w;
      dot[r][1] += c2.x * z.x + c2.y * z.y + c2.z * z.z + c2.w * z.w;
    }
  }
  int lane = tid & 63, w = tid >> 6;
#pragma unroll
  for (int r = 0; r < 4; ++r) {
    float bv = cc0 - 2.f * dot[r][0];
    int bi = k1;
    float v2 = cc1 - 2.f * dot[r][1];
    if (v2 < bv) {  // strict: prefer lower index on tie
      bv = v2;
      bi = k2;
    }
#pragma unroll
    for (int m = 32; m >= 1; m >>= 1) {
      float ov = __shfl_xor(bv, m);
      int oi = __shfl_xor(bi, m);
      if (ov < bv || (ov == bv && oi < bi)) {
        bv = ov;
        bi = oi;
      }
    }
    if (lane == 0) {
      wval[r][w] = bv;
      widx[r][w] = bi;
    }
  }
  __syncthreads();
  if (tid < 4) {
    float bb = wval[tid][0];
    int bi = widx[tid][0];
    for (int t = 1; t < 4; ++t)
      if (wval[tid][t] < bb || (wval[tid][t] == bb && widx[tid][t] < bi)) {
        bb = wval[tid][t];
        bi = widx[tid][t];
      }
    fidx[tid] = bi;
  }
  __syncthreads();
  for (int f = tid; f < 1024; f += 256) {
    int r = f >> 8, d = f & 255;
    float zv = zs[f];
    float zq = codebook[(size_t)fidx[r] * DIMn + d];
    out[(size_t)(row0 + r) * DIMn + d] = zv + (zq - zv);
  }
}

// ---------------------------------------------------------------------------
extern "C" void kernel_launch(void* const* d_in, const int* in_sizes, int n_in,
                              void* d_out, int out_size, void* d_ws,
                              size_t ws_size, hipStream_t stream) {
  const float* nodes_in = (const float*)d_in[0];
  const float* edges = (const float*)d_in[1];
  const float* edge_ln_g = (const float*)d_in[2];
  const float* edge_ln_b = (const float*)d_in[3];
  const float* ln1_g = (const float*)d_in[4];
  const float* ln1_b = (const float*)d_in[5];
  const float* w_exp = (const float*)d_in[6];
  const float* b_exp = (const float*)d_in[7];
  const float* w_q = (const float*)d_in[8];
  const float* b_q = (const float*)d_in[9];
  const float* w_kv = (const float*)d_in[10];
  const float* b_kv = (const float*)d_in[11];
  const float* w_ekv = (const float*)d_in[12];
  const float* b_ekv = (const float*)d_in[13];
  const float* w_out = (const float*)d_in[14];
  const float* b_out = (const float*)d_in[15];
  const float* gate1_w = (const float*)d_in[16];
  const float* ln2_g = (const float*)d_in[17];
  const float* ln2_b = (const float*)d_in[18];
  const float* w_ff1 = (const float*)d_in[19];
  const float* b_ff1 = (const float*)d_in[20];
  const float* w_ff2 = (const float*)d_in[21];
  const float* b_ff2 = (const float*)d_in[22];
  const float* gate2_w = (const float*)d_in[23];
  const float* codebook = (const float*)d_in[24];

  float* ws = (float*)d_ws;
  float* e_buf = ws;                    // 4194304
  float* cost = e_buf + 4194304;        // 4096
  float* sint = cost + 4096;            // 4096
  float* nodes = sint + 4096;           // 131072
  float* xln = nodes + 131072;          // 131072
  float* xe = xln + 131072;             // 262144
  float* qb = xe + 262144;              // 262144
  float* kvb = qb + 262144;             // 524288
  float* qeb = kvb + 524288;            // 262144
  float* attn = qeb + 262144;           // 262144
  float* proj = attn + 262144;          // 131072
  float* ff1 = proj + 131072;           // 524288

  hipMemcpyAsync(nodes, nodes_in, sizeof(float) * Bn * Nn * DIMn,
                 hipMemcpyDeviceToDevice, stream);
  edge_ln_kernel<<<256, 256, 0, stream>>>(edges, edge_ln_g, edge_ln_b, e_buf);
  rope_table_kernel<<<16, 256, 0, stream>>>(cost, sint);

  for (int l = 0; l < DEPTHn; ++l) {
    if (l == 0)
      ln_kernel<<<512, 256, 0, stream>>>(nodes, ln1_g, ln1_b, xln);
    // else: xln already holds LN1(nodes) from previous gate_ln fusion
    gemm_kernel<<<dim3(8, 16), 256, 0, stream>>>(
        xln, w_exp + l * 256 * 512, b_exp + l * 512, xe, 512, 512, 256, 0,
        cost, sint);
    gemm_kernel<<<dim3(8, 16), 256, 0, stream>>>(
        xe, w_q + l * 512 * 512, b_q + l * 512, qb, 512, 512, 512, 2, cost,
        sint);
    gemm_kernel<<<dim3(16, 16), 256, 0, stream>>>(
        xe, w_kv + l * 512 * 1024, b_kv + l * 1024, kvb, 512, 1024, 512, 3,
        cost, sint);
    qe_kernel<<<128, 256, 0, stream>>>(qb, w_ekv + l * 64 * 512, qeb);
    attn_kernel<<<4096, 128, 0, stream>>>(qb, kvb, qeb, e_buf,
                                          w_ekv + l * 64 * 512,
                                          b_ekv + l * 512, attn);
    gemm_kernel<<<dim3(4, 16), 256, 0, stream>>>(
        attn, w_out + l * 512 * 256, b_out + l * 256, proj, 512, 256, 512, 0,
        cost, sint);
    gate_ln_kernel<<<512, 256, 0, stream>>>(proj, nodes, gate1_w + l * 768,
                                            ln2_g + l * 256, ln2_b + l * 256,
                                            xln);
    gemm_kernel<<<dim3(16, 16), 256, 0, stream>>>(
        xln, w_ff1 + l * 256 * 1024, b_ff1 + l * 1024, ff1, 512, 1024, 256, 1,
        cost, sint);
    gemm_kernel<<<dim3(4, 16), 256, 0, stream>>>(
        ff1, w_ff2 + l * 1024 * 256, b_ff2 + l * 256, proj, 512, 256, 1024, 0,
        cost, sint);
    const float* nlng = (l + 1 < DEPTHn) ? ln1_g + (l + 1) * 256 : nullptr;
    const float* nlnb = (l + 1 < DEPTHn) ? ln1_b + (l + 1) * 256 : nullptr;
    gate_ln_kernel<<<512, 256, 0, stream>>>(proj, nodes, gate2_w + l * 768,
                                            nlng, nlnb, xln);
  }
  vq_kernel<<<128, 256, 0, stream>>>(nodes, codebook, (float*)d_out);
}